// Round 1
// baseline (306.057 us; speedup 1.0000x reference)
//
#include <hip/hip_runtime.h>
#include <hip/hip_bf16.h>

// Problem dims (fixed by reference)
#define NB 128
#define NT 4096
#define ND 64
#define NTOUT 4094   // NT-2

typedef __attribute__((ext_vector_type(8))) short bf16x8;
typedef __attribute__((ext_vector_type(4))) float f32x4;

__device__ __forceinline__ short bfb(float f) {
    __hip_bfloat16 h = __float2bfloat16(f);
    return __builtin_bit_cast(short, h);
}

__device__ __forceinline__ bf16x8 pack8(f32x4 a, f32x4 b) {
    bf16x8 r;
    r[0] = bfb(a[0]); r[1] = bfb(a[1]); r[2] = bfb(a[2]); r[3] = bfb(a[3]);
    r[4] = bfb(b[0]); r[5] = bfb(b[1]); r[6] = bfb(b[2]); r[7] = bfb(b[3]);
    return r;
}

// Kernel 1: conv(k=3) + ReLU + masked sum over t, accumulated into s_ws[b][64].
// Grid: 128 b * 16 chunks of 256 t-rows. Block: 256 threads = 4 waves.
// Wave w handles 4 16-row M-tiles at t = chunk*256 + w*64 + i*16.
// GEMM view: A (rows=t, K=192 contiguous floats from x[b][t][0]),
//            B[kidx][f] = W1[f*192 + kidx]  (f = output channel).
__global__ __launch_bounds__(256) void conv_pool_kernel(
    const float* __restrict__ x, const int* __restrict__ lengths,
    const float* __restrict__ W1, const float* __restrict__ b1,
    float* __restrict__ s_ws)
{
    const int b     = blockIdx.x >> 4;
    const int chunk = blockIdx.x & 15;
    const int nvalid = lengths[b] - 2;
    if (chunk * 256 >= nvalid) return;   // whole block masked out

    const int lane = threadIdx.x & 63;
    const int wave = threadIdx.x >> 6;
    const int lrow = lane & 15;   // M (t) or N (f) index within tile
    const int lkg  = lane >> 4;   // K-group (8 consecutive K per group)

    // --- load B fragments (weights) once: wfrag[nt][kk] ---
    bf16x8 wfrag[4][6];
    #pragma unroll
    for (int nt = 0; nt < 4; ++nt) {
        const float* wp = W1 + (nt * 16 + lrow) * 192 + lkg * 8;
        #pragma unroll
        for (int kk = 0; kk < 6; ++kk) {
            f32x4 w0 = *reinterpret_cast<const f32x4*>(wp + kk * 32);
            f32x4 w1v = *reinterpret_cast<const f32x4*>(wp + kk * 32 + 4);
            wfrag[nt][kk] = pack8(w0, w1v);
        }
    }
    float b1f[4];
    #pragma unroll
    for (int nt = 0; nt < 4; ++nt) b1f[nt] = b1[nt * 16 + lrow];

    float sums[4][4];
    #pragma unroll
    for (int nt = 0; nt < 4; ++nt)
        #pragma unroll
        for (int r = 0; r < 4; ++r) sums[nt][r] = 0.f;

    const float* xb = x + (size_t)b * (NT * ND);
    const int t_wave = chunk * 256 + wave * 64;

    for (int i = 0; i < 4; ++i) {
        const int t0 = t_wave + i * 16;
        int trow = t0 + lrow;
        int tload = trow > (NT - 3) ? (NT - 3) : trow;  // clamp halo reads
        const float* ap = xb + (size_t)tload * ND + lkg * 8;

        bf16x8 afrag[6];
        #pragma unroll
        for (int kk = 0; kk < 6; ++kk) {
            f32x4 a0 = *reinterpret_cast<const f32x4*>(ap + kk * 32);
            f32x4 a1 = *reinterpret_cast<const f32x4*>(ap + kk * 32 + 4);
            afrag[kk] = pack8(a0, a1);
        }

        f32x4 acc[4];
        #pragma unroll
        for (int nt = 0; nt < 4; ++nt) acc[nt] = (f32x4){0.f, 0.f, 0.f, 0.f};

        #pragma unroll
        for (int kk = 0; kk < 6; ++kk) {
            #pragma unroll
            for (int nt = 0; nt < 4; ++nt)
                acc[nt] = __builtin_amdgcn_mfma_f32_16x16x32_bf16(
                    afrag[kk], wfrag[nt][kk], acc[nt], 0, 0, 0);
        }

        // C layout: col(f) = lane&15, row(t) = (lane>>4)*4 + r   [measured m89/m91]
        #pragma unroll
        for (int r = 0; r < 4; ++r) {
            const int tg = t0 + lkg * 4 + r;
            const bool valid = tg < nvalid;
            #pragma unroll
            for (int nt = 0; nt < 4; ++nt) {
                float v = acc[nt][r] + b1f[nt];
                v = fmaxf(v, 0.f);
                sums[nt][r] += valid ? v : 0.f;
            }
        }
    }

    // reduce r, then across K-groups (lanes ^16, ^32); lanes 0..15 hold f sums
    #pragma unroll
    for (int nt = 0; nt < 4; ++nt) {
        float v = sums[nt][0] + sums[nt][1] + sums[nt][2] + sums[nt][3];
        v += __shfl_xor(v, 16, 64);
        v += __shfl_xor(v, 32, 64);
        if (lane < 16) atomicAdd(&s_ws[b * ND + nt * 16 + lane], v);
    }
}

// Kernel 2: per-batch pointwise (W2,b2) on pooled means + 3-layer MLP.
// Block per b, 256 threads. All fp32, tiny.
__global__ __launch_bounds__(256) void mlp_kernel(
    const float* __restrict__ s_ws, const int* __restrict__ lengths,
    const float* __restrict__ W2, const float* __restrict__ b2,
    const float* __restrict__ Wl1, const float* __restrict__ bl1,
    const float* __restrict__ Wl2, const float* __restrict__ bl2,
    const float* __restrict__ Wl3, const float* __restrict__ bl3,
    float* __restrict__ out)
{
    __shared__ float sh_s[64], sh_p[64], sh_z1[256], sh_z2[256];
    const int b = blockIdx.x, tid = threadIdx.x;

    if (tid < 64) {
        float nv = (float)(lengths[b] - 2);
        sh_s[tid] = s_ws[b * 64 + tid] / nv;
    }
    __syncthreads();

    if (tid < 64) {  // pooled[g] = sum_f s[f]*W2[g,f] + b2[g]
        float acc = b2[tid];
        const f32x4* wr = reinterpret_cast<const f32x4*>(W2 + tid * 64);
        const f32x4* vr = reinterpret_cast<const f32x4*>(sh_s);
        #pragma unroll 4
        for (int k = 0; k < 16; ++k) {
            f32x4 w = wr[k], v = vr[k];
            acc += w[0]*v[0] + w[1]*v[1] + w[2]*v[2] + w[3]*v[3];
        }
        sh_p[tid] = acc;
    }
    __syncthreads();

    {   // z1 = relu(pooled @ Wl1.T + bl1), 256 outs, K=64
        float acc = bl1[tid];
        const f32x4* wr = reinterpret_cast<const f32x4*>(Wl1 + tid * 64);
        const f32x4* vr = reinterpret_cast<const f32x4*>(sh_p);
        #pragma unroll 4
        for (int k = 0; k < 16; ++k) {
            f32x4 w = wr[k], v = vr[k];
            acc += w[0]*v[0] + w[1]*v[1] + w[2]*v[2] + w[3]*v[3];
        }
        sh_z1[tid] = fmaxf(acc, 0.f);
    }
    __syncthreads();

    {   // z2 = relu(z1 @ Wl2.T + bl2), 256 outs, K=256
        float acc = bl2[tid];
        const f32x4* wr = reinterpret_cast<const f32x4*>(Wl2 + tid * 256);
        const f32x4* vr = reinterpret_cast<const f32x4*>(sh_z1);
        #pragma unroll 4
        for (int k = 0; k < 64; ++k) {
            f32x4 w = wr[k], v = vr[k];
            acc += w[0]*v[0] + w[1]*v[1] + w[2]*v[2] + w[3]*v[3];
        }
        sh_z2[tid] = fmaxf(acc, 0.f);
    }
    __syncthreads();

    for (int o = tid; o < 512; o += 256) {  // out = z2 @ Wl3.T + bl3
        float acc = bl3[o];
        const f32x4* wr = reinterpret_cast<const f32x4*>(Wl3 + o * 256);
        const f32x4* vr = reinterpret_cast<const f32x4*>(sh_z2);
        #pragma unroll 4
        for (int k = 0; k < 64; ++k) {
            f32x4 w = wr[k], v = vr[k];
            acc += w[0]*v[0] + w[1]*v[1] + w[2]*v[2] + w[3]*v[3];
        }
        out[(size_t)b * 512 + o] = acc;
    }
}

extern "C" void kernel_launch(void* const* d_in, const int* in_sizes, int n_in,
                              void* d_out, int out_size, void* d_ws, size_t ws_size,
                              hipStream_t stream) {
    const float* x       = (const float*)d_in[0];
    const int*   lengths = (const int*)d_in[1];
    const float* W1      = (const float*)d_in[2];
    const float* b1      = (const float*)d_in[3];
    const float* W2      = (const float*)d_in[4];
    const float* b2      = (const float*)d_in[5];
    const float* Wl1     = (const float*)d_in[6];
    const float* bl1     = (const float*)d_in[7];
    const float* Wl2     = (const float*)d_in[8];
    const float* bl2     = (const float*)d_in[9];
    const float* Wl3     = (const float*)d_in[10];
    const float* bl3     = (const float*)d_in[11];
    float* out = (float*)d_out;

    float* s_ws = (float*)d_ws;  // [128][64] fp32 partial sums
    hipMemsetAsync(s_ws, 0, NB * ND * sizeof(float), stream);

    conv_pool_kernel<<<dim3(NB * 16), dim3(256), 0, stream>>>(x, lengths, W1, b1, s_ws);
    mlp_kernel<<<dim3(NB), dim3(256), 0, stream>>>(s_ws, lengths, W2, b2,
                                                   Wl1, bl1, Wl2, bl2, Wl3, bl3, out);
}

// Round 3
// 245.505 us; speedup vs baseline: 1.2466x; 1.2466x over previous
//
#include <hip/hip_runtime.h>
#include <hip/hip_bf16.h>

#define NB 128
#define NT 4096
#define ND 64
#define CH 128            // t-rows per block
#define NCHUNK 32         // NT / CH
#define NSEGS 33          // ceil((CH+2)/4) rows staged, 4 rows (1KB) per wave-issue

typedef __attribute__((ext_vector_type(8))) short bf16x8;
typedef __attribute__((ext_vector_type(4))) float f32x4;

__device__ __forceinline__ short bfb(float f) {
    __hip_bfloat16 h = __float2bfloat16(f);
    return __builtin_bit_cast(short, h);
}

__device__ __forceinline__ bf16x8 pack8(f32x4 a, f32x4 b) {
    bf16x8 r;
    r[0] = bfb(a[0]); r[1] = bfb(a[1]); r[2] = bfb(a[2]); r[3] = bfb(a[3]);
    r[4] = bfb(b[0]); r[5] = bfb(b[1]); r[6] = bfb(b[2]); r[7] = bfb(b[3]);
    return r;
}

// ---------------------------------------------------------------------------
// Setup: convert W1 (fp32 [64 f][3 k][64 d] = [64][192]) into bf16 MFMA
// B-fragment layout: wb[(nt*6+kk)*64 + lane] = bf16x8 of
// W1[f = nt*16 + (lane&15)][k = (lane>>4)*8 + kk*32 .. +8]
// ---------------------------------------------------------------------------
__global__ void setup_kernel(const float* __restrict__ W1, short* __restrict__ wb) {
    int idx = blockIdx.x * 256 + threadIdx.x;
    if (idx >= 4 * 6 * 64) return;
    int lane = idx & 63;
    int kk   = (idx >> 6) % 6;
    int nt   = idx / (6 * 64);
    const float* wp = W1 + (nt * 16 + (lane & 15)) * 192 + (lane >> 4) * 8 + kk * 32;
    bf16x8 r;
    #pragma unroll
    for (int j = 0; j < 8; ++j) r[j] = bfb(wp[j]);
    reinterpret_cast<bf16x8*>(wb)[idx] = r;
}

// ---------------------------------------------------------------------------
// Conv(k=3, valid) + ReLU + masked sum over t  ->  s_sum[b][64]
// Grid: NB * NCHUNK blocks, 256 threads (4 waves). Block stages
// x[t0 .. t0+131] (fp32) into LDS via global_load_lds with XOR unit-swizzle,
// each wave computes 2 MFMA M-tiles of 16 t-rows.
// ---------------------------------------------------------------------------
__global__ __launch_bounds__(256) void conv_pool_kernel(
    const float* __restrict__ x, const int* __restrict__ lengths,
    const short* __restrict__ wb, const float* __restrict__ b1,
    float* __restrict__ s_sum)
{
    __shared__ float lds[NSEGS * 256];   // 33 KB: 132 rows x 64 floats
    __shared__ float sh_red[4 * 64];

    const int b      = blockIdx.x >> 5;
    const int chunk  = blockIdx.x & (NCHUNK - 1);
    const int nvalid = lengths[b] - 2;
    const int t0     = chunk * CH;
    if (t0 >= nvalid) return;            // block-uniform early exit

    const int lane = threadIdx.x & 63;
    const int wave = threadIdx.x >> 6;
    const int lrow = lane & 15;
    const int lkg  = lane >> 4;

    const int rows_needed = min(CH + 2, nvalid - t0 + 2);
    const float* xb = x + (size_t)b * (NT * ND);

    // ---- stage x -> LDS (fire-and-forget). LDS[row][u] <- x[row][u ^ (row&7)]
    {
        const int unit = lane & 15;
        const int rl4  = lane >> 4;
        for (int s = wave; s < NSEGS; s += 4) {
            if (s * 4 < rows_needed) {
                int row_local = s * 4 + rl4;
                int rg = t0 + row_local; if (rg > NT - 1) rg = NT - 1;
                int su = unit ^ (row_local & 7);
                const float* src = xb + (size_t)rg * ND + su * 4;
                __builtin_amdgcn_global_load_lds(
                    (const __attribute__((address_space(1))) void*)src,
                    (__attribute__((address_space(3))) void*)&lds[s * 256],
                    16, 0, 0);
            }
        }
    }

    // ---- weight fragments: 24 coalesced 16B bf16 loads (overlap with staging)
    bf16x8 wfrag[4][6];
    #pragma unroll
    for (int nt = 0; nt < 4; ++nt)
        #pragma unroll
        for (int kk = 0; kk < 6; ++kk)
            wfrag[nt][kk] = reinterpret_cast<const bf16x8*>(wb)[(nt * 6 + kk) * 64 + lane];
    float b1f[4];
    #pragma unroll
    for (int nt = 0; nt < 4; ++nt) b1f[nt] = b1[nt * 16 + lrow];

    __syncthreads();                      // drains global_load_lds (vmcnt 0)

    float sums[4] = {0.f, 0.f, 0.f, 0.f};

    #pragma unroll
    for (int i = 0; i < 2; ++i) {
        const int tile = wave + i * 4;    // 8 tiles of 16 rows
        const int tl0  = tile * 16;
        if (t0 + tl0 < nvalid) {          // wave-uniform guard
            f32x4 acc[4];
            #pragma unroll
            for (int nt = 0; nt < 4; ++nt) acc[nt] = (f32x4){0.f, 0.f, 0.f, 0.f};

            #pragma unroll
            for (int kk = 0; kk < 6; ++kk) {
                const int xrl = tl0 + lrow + (kk >> 1);        // staged row
                const int e   = lkg * 2 + (kk & 1) * 8;        // 16B-unit index
                const int sw  = xrl & 7;
                f32x4 a0 = *reinterpret_cast<const f32x4*>(&lds[xrl * 64 + ((e ^ sw) << 2)]);
                f32x4 a1 = *reinterpret_cast<const f32x4*>(&lds[xrl * 64 + (((e + 1) ^ sw) << 2)]);
                bf16x8 afrag = pack8(a0, a1);
                #pragma unroll
                for (int nt = 0; nt < 4; ++nt)
                    acc[nt] = __builtin_amdgcn_mfma_f32_16x16x32_bf16(
                        afrag, wfrag[nt][kk], acc[nt], 0, 0, 0);
            }

            // C layout: col(f)=lane&15, row(t)=(lane>>4)*4+r  [m89/m91]
            #pragma unroll
            for (int r = 0; r < 4; ++r) {
                const bool valid = (t0 + tl0 + lkg * 4 + r) < nvalid;
                #pragma unroll
                for (int nt = 0; nt < 4; ++nt) {
                    float v = fmaxf(acc[nt][r] + b1f[nt], 0.f);
                    if (valid) sums[nt] += v;
                }
            }
        }
    }

    // ---- reduce: r-sums already folded; fold K-groups, then waves, 64 atomics
    #pragma unroll
    for (int nt = 0; nt < 4; ++nt) {
        float v = sums[nt];
        v += __shfl_xor(v, 16, 64);
        v += __shfl_xor(v, 32, 64);
        if (lane < 16) sh_red[wave * 64 + nt * 16 + lane] = v;
    }
    __syncthreads();
    if (threadIdx.x < 64) {
        float tot = sh_red[threadIdx.x] + sh_red[64 + threadIdx.x] +
                    sh_red[128 + threadIdx.x] + sh_red[192 + threadIdx.x];
        atomicAdd(&s_sum[b * 64 + threadIdx.x], tot);
    }
}

// ---------------------------------------------------------------------------
// Per-batch pointwise (W2,b2) on pooled mean + 3-layer MLP. f32x4 accumulators
// (4 independent FMA chains) to break serial dependence.
// ---------------------------------------------------------------------------
__global__ __launch_bounds__(256) void mlp_kernel(
    const float* __restrict__ s_sum, const int* __restrict__ lengths,
    const float* __restrict__ W2, const float* __restrict__ b2,
    const float* __restrict__ Wl1, const float* __restrict__ bl1,
    const float* __restrict__ Wl2, const float* __restrict__ bl2,
    const float* __restrict__ Wl3, const float* __restrict__ bl3,
    float* __restrict__ out)
{
    __shared__ float sh_s[64], sh_p[64], sh_z1[256], sh_z2[256];
    const int b = blockIdx.x, tid = threadIdx.x;

    if (tid < 64)
        sh_s[tid] = s_sum[b * 64 + tid] / (float)(lengths[b] - 2);
    __syncthreads();

    if (tid < 64) {   // pooled[g] = sum_f mean[f]*W2[g,f] + b2[g]
        f32x4 acc = {0.f, 0.f, 0.f, 0.f};
        const f32x4* wr = reinterpret_cast<const f32x4*>(W2 + tid * 64);
        const f32x4* vr = reinterpret_cast<const f32x4*>(sh_s);
        #pragma unroll
        for (int k = 0; k < 16; ++k) acc += wr[k] * vr[k];
        sh_p[tid] = b2[tid] + acc[0] + acc[1] + acc[2] + acc[3];
    }
    __syncthreads();

    {   // z1 = relu(pooled @ Wl1.T + bl1)
        f32x4 acc = {0.f, 0.f, 0.f, 0.f};
        const f32x4* wr = reinterpret_cast<const f32x4*>(Wl1 + tid * 64);
        const f32x4* vr = reinterpret_cast<const f32x4*>(sh_p);
        #pragma unroll
        for (int k = 0; k < 16; ++k) acc += wr[k] * vr[k];
        sh_z1[tid] = fmaxf(bl1[tid] + acc[0] + acc[1] + acc[2] + acc[3], 0.f);
    }
    __syncthreads();

    {   // z2 = relu(z1 @ Wl2.T + bl2)
        f32x4 a0 = {0.f, 0.f, 0.f, 0.f}, a1 = {0.f, 0.f, 0.f, 0.f};
        const f32x4* wr = reinterpret_cast<const f32x4*>(Wl2 + tid * 256);
        const f32x4* vr = reinterpret_cast<const f32x4*>(sh_z1);
        #pragma unroll
        for (int k = 0; k < 64; k += 2) { a0 += wr[k] * vr[k]; a1 += wr[k + 1] * vr[k + 1]; }
        f32x4 a = a0 + a1;
        sh_z2[tid] = fmaxf(bl2[tid] + a[0] + a[1] + a[2] + a[3], 0.f);
    }
    __syncthreads();

    {   // out = z2 @ Wl3.T + bl3 (2 rows per thread, independent chains)
        f32x4 a0 = {0.f, 0.f, 0.f, 0.f}, a1 = {0.f, 0.f, 0.f, 0.f};
        const f32x4* w0 = reinterpret_cast<const f32x4*>(Wl3 + (size_t)tid * 256);
        const f32x4* w1 = reinterpret_cast<const f32x4*>(Wl3 + (size_t)(tid + 256) * 256);
        const f32x4* vr = reinterpret_cast<const f32x4*>(sh_z2);
        #pragma unroll
        for (int k = 0; k < 64; ++k) { a0 += w0[k] * vr[k]; a1 += w1[k] * vr[k]; }
        out[(size_t)b * 512 + tid]       = bl3[tid]       + a0[0] + a0[1] + a0[2] + a0[3];
        out[(size_t)b * 512 + 256 + tid] = bl3[tid + 256] + a1[0] + a1[1] + a1[2] + a1[3];
    }
}

extern "C" void kernel_launch(void* const* d_in, const int* in_sizes, int n_in,
                              void* d_out, int out_size, void* d_ws, size_t ws_size,
                              hipStream_t stream) {
    const float* x       = (const float*)d_in[0];
    const int*   lengths = (const int*)d_in[1];
    const float* W1      = (const float*)d_in[2];
    const float* b1      = (const float*)d_in[3];
    const float* W2      = (const float*)d_in[4];
    const float* b2      = (const float*)d_in[5];
    const float* Wl1     = (const float*)d_in[6];
    const float* bl1     = (const float*)d_in[7];
    const float* Wl2     = (const float*)d_in[8];
    const float* bl2     = (const float*)d_in[9];
    const float* Wl3     = (const float*)d_in[10];
    const float* bl3     = (const float*)d_in[11];
    float* out = (float*)d_out;

    float* s_sum = (float*)d_ws;                         // 32 KB fp32 sums
    short* wb    = (short*)((char*)d_ws + NB * ND * 4);  // 24 KB bf16 W1 frags

    hipMemsetAsync(s_sum, 0, NB * ND * sizeof(float), stream);
    setup_kernel<<<dim3(6), dim3(256), 0, stream>>>(W1, wb);
    conv_pool_kernel<<<dim3(NB * NCHUNK), dim3(256), 0, stream>>>(x, lengths, wb, b1, s_sum);
    mlp_kernel<<<dim3(NB), dim3(256), 0, stream>>>(s_sum, lengths, W2, b2,
                                                   Wl1, bl1, Wl2, bl2, Wl3, bl3, out);
}